// Round 4
// baseline (1456.323 us; speedup 1.0000x reference)
//
#include <hip/hip_runtime.h>

typedef _Float16 half8 __attribute__((ext_vector_type(8)));
typedef float floatx4 __attribute__((ext_vector_type(4)));

#define T_STEPS 20
#define NSEQ 131072
#define HID 192
#define ROWS 32
#define HPAD 200            // fp16 elems per LDS h-row (400 B stride: 2-way b128 aliasing, best possible)
#define WOFF 147456         // frags: wout section (3072 halfs)
#define XOFF 150528         // frags: w_ih/bias section (unused by kernel now, kept for layout stability)
#define FR_TOTAL (XOFF + 6144)

#define MFMA16(a, b, c) __builtin_amdgcn_mfma_f32_16x16x32_f16((a), (b), (c), 0, 0, 0)

// Rewrite w_hh / w_out into MFMA B-fragment order (fp16).
// B-frag 16x16x32: lane L = q*16 + n holds k = q*8..q*8+7 of column n.
// W_hh section: [12 ht][6 kc][4 g][64 lanes][8 e]
__global__ void build_frags(const float* __restrict__ whh,
                            const float* __restrict__ wout,
                            const float* __restrict__ wih,
                            const float* __restrict__ bih,
                            const float* __restrict__ bhh,
                            _Float16* __restrict__ dst) {
    int i = blockIdx.x * 256 + threadIdx.x;
    if (i < WOFF) {
        int e = i & 7, L = (i >> 3) & 63, g = (i >> 9) & 3, u = i >> 11;
        int kc = u % 6, ht = u / 6;
        int n = L & 15, q = L >> 4;
        dst[i] = (_Float16)whh[(size_t)(g * HID + ht * 16 + n) * HID + kc * 32 + q * 8 + e];
    } else if (i < XOFF) {
        int k = i - WOFF;
        int e = k & 7, L = (k >> 3) & 63, kc = k >> 9;
        int n = L & 15, q = L >> 4;
        dst[i] = (_Float16)((n < 2) ? wout[n * HID + kc * 32 + q * 8 + e] : 0.f);
    }
}

// 768 threads = 12 waves, 1 block/CU (VGPR-capped at 3 waves/EU). Skewed
// two-half schedule with instruction-level interleave. All W_hh B-frags
// VGPR/AGPR-resident (96 regs, loaded once) -> LDS pipe drops from ~180 to
// ~72 b128 reads per CU-segment. x*W_ih + bias is a 32-fma VALU acc-init
// (moves work off the matrix pipe; kills the 90%-zero kc6 MFMA slice).
__global__ __launch_bounds__(768) __attribute__((amdgpu_waves_per_eu(3, 3)))
void lstm_fused_kernel(
    const float* __restrict__ obs,       // [20][N][2]
    const float* __restrict__ h0,        // [N][192]
    const float* __restrict__ w_ih,      // [768][2]
    const float* __restrict__ b_ih,      // [768]
    const float* __restrict__ b_hh,      // [768]
    const float* __restrict__ b_out,     // [2]
    const _Float16* __restrict__ frags,  // whh + wout fragments (fp16)
    float* __restrict__ out)             // [20][N][2]
{
    __shared__ _Float16 h0b[2][16][HPAD];            // batch rows 0..15, dbuf (12800 B)
    __shared__ _Float16 h1b[16][HPAD];               // batch rows 16..31 (6400 B)
    __shared__ _Float16 wo_lds[3072];                // wout frags (6144 B)
    __shared__ alignas(16) float2 x_all[T_STEPS][ROWS];  // all steps' x (5120 B)

    const int tid  = threadIdx.x;
    const int wave = tid >> 6;
    const int lane = tid & 63;
    const int quad = lane >> 4;
    const int l16  = lane & 15;
    const int ht   = wave;
    const int base = blockIdx.x * ROWS;
    const int j    = ht * 16 + l16;

    // ---- resident weights: whh kc0..5 B-frags (24 half8 = 96 regs) ----
    half8 bw[24];
#pragma unroll
    for (int kc = 0; kc < 6; ++kc)
#pragma unroll
        for (int g = 0; g < 4; ++g)
            bw[kc * 4 + g] = *(const half8*)&frags[(((ht * 6 + kc) * 4 + g) << 9) + lane * 8];

    // per-lane gate-column constants: combined bias + w_ih rows (12 regs)
    float bs[4], w0[4], w1[4];
#pragma unroll
    for (int g = 0; g < 4; ++g) {
        bs[g] = b_ih[g * HID + j] + b_hh[g * HID + j];
        w0[g] = w_ih[(g * HID + j) * 2];
        w1[g] = w_ih[(g * HID + j) * 2 + 1];
    }
    const float bo_n = (l16 < 2) ? b_out[l16] : 0.f;

    // ---- staging: wout frags, x for all steps, h0 -> fp16 rows ----
    if (tid < 384) ((half8*)wo_lds)[tid] = *(const half8*)&frags[WOFF + tid * 8];
    if (tid < T_STEPS * ROWS) {
        int t = tid >> 5, r = tid & 31;
        int src = (t == 0) ? 0 : (t - 1);
        x_all[t][r] = *(const float2*)&obs[((size_t)src * NSEQ + base + r) * 2];
    }
    for (int i = tid; i < ROWS * HID / 4; i += 768) {
        float4 v = *(const float4*)&h0[(size_t)base * HID + i * 4];
        int row = (i * 4) / HID, k = i * 4 - row * HID;
        _Float16* d = (row < 16) ? &h0b[0][row][k] : &h1b[row - 16][k];
        d[0] = (_Float16)v.x; d[1] = (_Float16)v.y;
        d[2] = (_Float16)v.z; d[3] = (_Float16)v.w;
    }
    __syncthreads();

    float c[8];
#pragma unroll
    for (int i = 0; i < 8; ++i) c[i] = 0.f;

    // gate build for one 16-row batch half: VALU acc-init (x*w_ih + biases)
    // + 6 K-slices of resident-B MFMAs (A from LDS h rows)
    auto build = [&](const _Float16* hb, const float2* xr, floatx4* aN) {
        const _Float16* ar = hb + l16 * HPAD;
        float4 x01 = *(const float4*)&xr[quad * 4];      // rows quad*4+0,1
        float4 x23 = *(const float4*)&xr[quad * 4 + 2];  // rows quad*4+2,3
#pragma unroll
        for (int g = 0; g < 4; ++g) {
            aN[g][0] = bs[g] + x01.x * w0[g] + x01.y * w1[g];
            aN[g][1] = bs[g] + x01.z * w0[g] + x01.w * w1[g];
            aN[g][2] = bs[g] + x23.x * w0[g] + x23.y * w1[g];
            aN[g][3] = bs[g] + x23.z * w0[g] + x23.w * w1[g];
        }
#pragma unroll
        for (int kc = 0; kc < 6; ++kc) {
            half8 a = *(const half8*)(ar + kc * 32 + quad * 8);
#pragma unroll
            for (int g = 0; g < 4; ++g)
                aN[g] = MFMA16(a, bw[kc * 4 + g], aN[g]);
        }
    };

    // activation (rational form: 5 exp2 + 2 rcp per cell)
    auto act = [&](floatx4* aO, _Float16* hw, int cb) {
#pragma unroll
        for (int r = 0; r < 4; ++r) {
            const int row = quad * 4 + r;
            const float Ai = __builtin_amdgcn_exp2f(-1.4426950408889634f * aO[0][r]);
            const float Af = __builtin_amdgcn_exp2f(-1.4426950408889634f * aO[1][r]);
            const float Bg = __builtin_amdgcn_exp2f( 2.8853900817779268f * aO[2][r]);
            const float Co = __builtin_amdgcn_exp2f(-1.4426950408889634f * aO[3][r]);
            const float Qf = 1.f + Af;
            const float Pg = (1.f + Ai) * (Bg + 1.f);
            const float Nn = c[cb + r] * Pg + Qf * (Bg - 1.f);
            const float cn = Nn * __builtin_amdgcn_rcpf(Qf * Pg);
            c[cb + r] = cn;
            const float Dc = __builtin_amdgcn_exp2f(2.8853900817779268f * cn);
            const float hv = (Dc - 1.f) * __builtin_amdgcn_rcpf((1.f + Co) * (Dc + 1.f));
            hw[row * HPAD + j] = (_Float16)hv;
        }
    };

    // T19 pin: interleave the 24 MFMAs (this half) with the other half's
    // activation VALU. Per segment: ~8 ds_read, 24 MFMA, ~140 VALU, 4 ds_write.
    auto sched_pattern = [&]() {
        __builtin_amdgcn_sched_group_barrier(0x002, 12, 0);      // acc-init VALU
#pragma unroll
        for (int u = 0; u < 6; ++u) {
            __builtin_amdgcn_sched_group_barrier(0x100, 1, 0);   // DS_READ (A-frag)
            __builtin_amdgcn_sched_group_barrier(0x008, 4, 0);   // MFMA
            __builtin_amdgcn_sched_group_barrier(0x002, 18, 0);  // VALU (act)
        }
        __builtin_amdgcn_sched_group_barrier(0x200, 4, 0);       // DS_WRITE (h)
    };

    // wout for one 16-row half (wave 0 -> rows 0..15, wave 1 -> rows 16..31)
    auto wout1 = [&](int ot, const _Float16* hbase) {
        const _Float16* ar = hbase + l16 * HPAD;
        floatx4 ao = {bo_n, bo_n, bo_n, bo_n};
#pragma unroll
        for (int kc = 0; kc < 6; ++kc) {
            half8 a = *(const half8*)(ar + kc * 32 + quad * 8);
            half8 b = *(const half8*)&wo_lds[kc * 512 + lane * 8];
            ao = MFMA16(a, b, ao);
        }
        if (l16 < 2) {
#pragma unroll
            for (int r = 0; r < 4; ++r)
                out[((size_t)ot * NSEQ + base + ht * 16 + quad * 4 + r) * 2 + l16] = ao[r];
        }
    };

    // ---- prologue: accA = gates for batch rows 0-15 at t=0 ----
    floatx4 accA[4], accB[4];
    build(&h0b[0][0][0], &x_all[0][0], accA);

    for (int t = 0; t < T_STEPS - 1; ++t) {
        _Float16* h0n = &h0b[(t + 1) & 1][0][0];

        // ===== segment X: gates rows16-31 step t || act(accA) -> h_{t+1} rows0-15 =====
        build(&h1b[0][0], &x_all[t][16], accB);
        act(accA, h0n, 0);
        sched_pattern();
        if (ht < 2 && t > 0)
            wout1(t - 1, (ht == 0) ? &h0b[t & 1][0][0] : &h1b[0][0]);
        __syncthreads();

        // ===== segment Y: gates rows0-15 step t+1 || act(accB) -> h_{t+1} rows16-31 =====
        build(h0n, &x_all[t + 1][0], accA);
        act(accB, &h1b[0][0], 4);
        sched_pattern();
        __syncthreads();
    }

    // ---- t = 19 peeled ----
    build(&h1b[0][0], &x_all[T_STEPS - 1][16], accB);
    act(accA, &h0b[0][0][0], 0);                  // h_20 rows 0-15 -> h0b[0]
    sched_pattern();
    if (ht < 2)
        wout1(18, (ht == 0) ? &h0b[1][0][0] : &h1b[0][0]);   // h_19
    __syncthreads();
    act(accB, &h1b[0][0], 4);                     // h_20 rows 16-31
    __syncthreads();
    if (ht < 2)
        wout1(19, (ht == 0) ? &h0b[0][0][0] : &h1b[0][0]);   // h_20
}

extern "C" void kernel_launch(void* const* d_in, const int* in_sizes, int n_in,
                              void* d_out, int out_size, void* d_ws, size_t ws_size,
                              hipStream_t stream) {
    const float* obs  = (const float*)d_in[0];
    const float* h0   = (const float*)d_in[1];
    const float* wih  = (const float*)d_in[2];
    const float* whh  = (const float*)d_in[3];
    const float* bih  = (const float*)d_in[4];
    const float* bhh  = (const float*)d_in[5];
    const float* wout = (const float*)d_in[6];
    const float* bout = (const float*)d_in[7];
    float* out = (float*)d_out;
    _Float16* frags = (_Float16*)d_ws;   // 301056 B used

    build_frags<<<(FR_TOTAL + 255) / 256, 256, 0, stream>>>(whh, wout, wih, bih, bhh, frags);
    lstm_fused_kernel<<<NSEQ / ROWS, 768, 0, stream>>>(
        obs, h0, wih, bih, bhh, bout, frags, out);
}